// Round 4
// baseline (320.683 us; speedup 1.0000x reference)
//
#include <hip/hip_runtime.h>

#define S_LEN 8192
#define D_DIM 2048
#define HD    128
#define KVB   32       // kv tile rows
#define NCH   8        // kv chunks (flash-decoding split)

typedef __attribute__((ext_vector_type(8))) short bf16x8;
typedef __attribute__((ext_vector_type(4))) float f32x4;

__device__ __forceinline__ unsigned short f2bf(float f) {
  unsigned int u = __float_as_uint(f);
  u += 0x7fffu + ((u >> 16) & 1u);
  return (unsigned short)(u >> 16);
}
__device__ __forceinline__ float bf2f(unsigned short h) {
  return __uint_as_float(((unsigned int)h) << 16);
}

__device__ __forceinline__ void glds16(const void* g, const short* l) {
  __builtin_amdgcn_global_load_lds(
      (const __attribute__((address_space(1))) void*)g,
      (__attribute__((address_space(3))) void*)l, 16, 0, 0);
}

// ---------------- split x into hi/lo bf16 ----------------
__global__ __launch_bounds__(256)
void split_x_kernel(const float* __restrict__ x,
                    unsigned short* __restrict__ xh, unsigned short* __restrict__ xl)
{
  const size_t n4 = (size_t)S_LEN * D_DIM / 4;
  size_t idx = (size_t)blockIdx.x * 256 + threadIdx.x;
  const size_t stride = (size_t)gridDim.x * 256;
  for (; idx < n4; idx += stride) {
    float4 v = ((const float4*)x)[idx];
    ushort4 h, l;
#pragma unroll
    for (int j = 0; j < 4; ++j) {
      float f = ((const float*)&v)[j];
      unsigned short hb = f2bf(f);
      ((unsigned short*)&h)[j] = hb;
      ((unsigned short*)&l)[j] = f2bf(f - bf2f(hb));
    }
    ((ushort4*)xh)[idx] = h;
    ((ushort4*)xl)[idx] = l;
  }
}

// ---------------- transpose+split w: wT[mode][col][k] hi/lo bf16 ----------------
__global__ __launch_bounds__(256)
void split_w_kernel(const float* __restrict__ wq, const float* __restrict__ wk,
                    const float* __restrict__ wv,
                    unsigned short* __restrict__ wTh, unsigned short* __restrict__ wTl)
{
  const int mode = blockIdx.y;
  const float* __restrict__ w = (mode == 0) ? wq : (mode == 1) ? wk : wv;
  unsigned short* __restrict__ oh = wTh + (size_t)mode * HD * D_DIM;
  unsigned short* __restrict__ ol = wTl + (size_t)mode * HD * D_DIM;
  const int k0 = blockIdx.x * 64;

  __shared__ float ws[64][132];
  const int t = threadIdx.x;
#pragma unroll
  for (int i = 0; i < 8; ++i) {
    int idx = t + i * 256;
    int row = idx >> 5;
    int c4  = idx & 31;
    *(float4*)&ws[row][c4 * 4] = *(const float4*)(w + (size_t)(k0 + row) * HD + c4 * 4);
  }
  __syncthreads();
#pragma unroll
  for (int i = 0; i < 4; ++i) {
    int task = t + i * 256;
    int col = task >> 3;
    int kc  = task & 7;
    ushort4 h[2], l[2];
#pragma unroll
    for (int e = 0; e < 8; ++e) {
      float f = ws[kc * 8 + e][col];
      unsigned short hb = f2bf(f);
      ((unsigned short*)&h[e >> 2])[e & 3] = hb;
      ((unsigned short*)&l[e >> 2])[e & 3] = f2bf(f - bf2f(hb));
    }
    size_t off = (size_t)col * D_DIM + k0 + kc * 8;
    *(ushort4*)(oh + off)     = h[0];
    *(ushort4*)(oh + off + 4) = h[1];
    *(ushort4*)(ol + off)     = l[0];
    *(ushort4*)(ol + off + 4) = l[1];
  }
}

// ---------------- projection GEMM: split-bf16 MFMA (unchanged) ----------------
__global__ __launch_bounds__(256)
void proj_kernel(const unsigned short* __restrict__ xh, const unsigned short* __restrict__ xl,
                 const unsigned short* __restrict__ wTh, const unsigned short* __restrict__ wTl,
                 unsigned short* __restrict__ q_hi, unsigned short* __restrict__ q_lo,
                 unsigned short* __restrict__ k_hi, unsigned short* __restrict__ k_lo,
                 unsigned short* __restrict__ vT)
{
  __shared__ short sm[2][12288];

  const int mode = blockIdx.y;
  const int mt   = blockIdx.x;
  const bool split = (mode < 2);

  const unsigned short* gxh = xh + (size_t)mt * 64 * D_DIM;
  const unsigned short* gxl = xl + (size_t)mt * 64 * D_DIM;
  const unsigned short* gwh = wTh + (size_t)mode * HD * D_DIM;
  const unsigned short* gwl = wTl + (size_t)mode * HD * D_DIM;

  const int t   = threadIdx.x;
  const int wid = t >> 6;
  const int ln  = t & 63;
  const int cl  = ln & 15;
  const int g4  = ln >> 4;

  auto stage = [&](int kt, int buf) {
    short* b = sm[buf];
    {
      int slot = wid * 64 + ln;
      int row = slot >> 2, sc = slot & 3;
      int kof = (sc ^ (row & 3)) * 8;
      glds16(gxh + (size_t)row * D_DIM + kt + kof, b + wid * 512);
      if (split)
        glds16(gxl + (size_t)row * D_DIM + kt + kof, b + 2048 + wid * 512);
    }
#pragma unroll
    for (int g = 0; g < 2; ++g) {
      int slot = g * 256 + wid * 64 + ln;
      int col = slot >> 2, sc = slot & 3;
      int kof = (sc ^ (col & 3)) * 8;
      glds16(gwh + (size_t)col * D_DIM + kt + kof, b + 4096 + (g * 256 + wid * 64) * 8);
      if (split)
        glds16(gwl + (size_t)col * D_DIM + kt + kof, b + 8192 + (g * 256 + wid * 64) * 8);
    }
  };

  f32x4 acc[2][4];
#pragma unroll
  for (int m = 0; m < 2; ++m)
#pragma unroll
    for (int n = 0; n < 4; ++n) acc[m][n] = f32x4{0.f, 0.f, 0.f, 0.f};

  stage(0, 0);
  __syncthreads();

  for (int kt = 0, step = 0; kt < D_DIM; kt += 32, ++step) {
    const int cur = step & 1;
    if (kt + 32 < D_DIM) stage(kt + 32, cur ^ 1);

    const short* b = sm[cur];
    bf16x8 a_h[2], a_l[2], b_h[4], b_l[4];
#pragma unroll
    for (int m = 0; m < 2; ++m) {
      int row = (wid >> 1) * 32 + m * 16 + cl;
      int byte = row * 64 + ((g4 ^ (row & 3)) << 4);
      a_h[m] = *(const bf16x8*)((const char*)b + byte);
      if (split) a_l[m] = *(const bf16x8*)((const char*)b + 4096 + byte);
    }
#pragma unroll
    for (int n = 0; n < 4; ++n) {
      int col = (wid & 1) * 64 + n * 16 + cl;
      int byte = col * 64 + ((g4 ^ (col & 3)) << 4);
      b_h[n] = *(const bf16x8*)((const char*)b + 8192 + byte);
      if (split) b_l[n] = *(const bf16x8*)((const char*)b + 16384 + byte);
    }

#pragma unroll
    for (int m = 0; m < 2; ++m)
#pragma unroll
      for (int n = 0; n < 4; ++n)
        acc[m][n] = __builtin_amdgcn_mfma_f32_16x16x32_bf16(a_h[m], b_h[n], acc[m][n], 0, 0, 0);
    if (split) {
#pragma unroll
      for (int m = 0; m < 2; ++m)
#pragma unroll
        for (int n = 0; n < 4; ++n) {
          acc[m][n] = __builtin_amdgcn_mfma_f32_16x16x32_bf16(a_l[m], b_h[n], acc[m][n], 0, 0, 0);
          acc[m][n] = __builtin_amdgcn_mfma_f32_16x16x32_bf16(a_h[m], b_l[n], acc[m][n], 0, 0, 0);
        }
    }
    __syncthreads();
  }

  const int rbase = mt * 64 + (wid >> 1) * 32 + g4 * 4;
  const int cbase = (wid & 1) * 64 + cl;

  if (mode < 2) {
    const float scale = (mode == 0) ? 0.08838834764831843f : 1.0f;
    unsigned short* __restrict__ oh = (mode == 0) ? q_hi : k_hi;
    unsigned short* __restrict__ ol = (mode == 0) ? q_lo : k_lo;
#pragma unroll
    for (int m = 0; m < 2; ++m)
#pragma unroll
      for (int n = 0; n < 4; ++n)
#pragma unroll
        for (int r = 0; r < 4; ++r) {
          float val = acc[m][n][r] * scale;
          unsigned short hb = f2bf(val);
          size_t off = (size_t)(rbase + m * 16 + r) * HD + cbase + n * 16;
          oh[off] = hb;
          ol[off] = f2bf(val - bf2f(hb));
        }
  } else {
#pragma unroll
    for (int m = 0; m < 2; ++m)
#pragma unroll
      for (int n = 0; n < 4; ++n) {
        ushort4 o;
#pragma unroll
        for (int r = 0; r < 4; ++r) ((unsigned short*)&o)[r] = f2bf(acc[m][n][r]);
        int col = cbase + n * 16;
        *(ushort4*)(vT + (size_t)col * S_LEN + rbase + m * 16) = o;
      }
  }
}

// ---------------- MFMA flash attention v2: R=4, 2-wave blocks, deferred softmax ----------------
// 256 blocks = 32 pairs x 8 chunks; block = 2 waves x 64 q-rows (128-row tile);
// tiles paired (T, 63-T); KVB=32; partials (o, m, l) per (tile, chunk)
__global__ __launch_bounds__(128)
void attn_kernel(const unsigned short* __restrict__ q_hi, const unsigned short* __restrict__ q_lo,
                 const unsigned short* __restrict__ k_hi, const unsigned short* __restrict__ k_lo,
                 const unsigned short* __restrict__ vT,
                 float* __restrict__ part_o, float* __restrict__ part_ml)
{
  __shared__ short ls_kh[2][4096];   // 32 x 128 bf16, swizzled
  __shared__ short ls_kl[2][4096];
  __shared__ short ls_v [2][4096];   // v^T 128 x 32 bf16, swizzled
  __shared__ short ls_p [2][64 * 40]; // per-wave P [64 q][32 k], stride 40

  const int t   = threadIdx.x;
  const int wid = t >> 6;
  const int ln  = t & 63;
  const int cl  = ln & 15;
  const int g4  = ln >> 4;
  const int pairId = blockIdx.x >> 3;   // 0..31
  const int chunk  = blockIdx.x & 7;

  short* pw = ls_p[wid];

  auto stage = [&](int j, int buf) {
    const unsigned short* gkh = k_hi + (size_t)j * KVB * HD;
    const unsigned short* gkl = k_lo + (size_t)j * KVB * HD;
    const unsigned short* gv  = vT + (size_t)j * KVB;
#pragma unroll
    for (int i = 0; i < 4; ++i) {
      int slot = i * 128 + t;             // 0..511
      int row = slot >> 4, sc = slot & 15;
      int c16 = sc ^ (row & 7);
      glds16(gkh + row * HD + c16 * 8, &ls_kh[buf][(i * 128 + wid * 64) * 8]);
      glds16(gkl + row * HD + c16 * 8, &ls_kl[buf][(i * 128 + wid * 64) * 8]);
    }
#pragma unroll
    for (int i = 0; i < 4; ++i) {
      int slot = i * 128 + t;
      int d = slot >> 2, sc = slot & 3;
      int sub = sc ^ ((d & 3) ^ ((d >> 2) & 3));
      glds16(gv + (size_t)d * S_LEN + sub * 8, &ls_v[buf][(i * 128 + wid * 64) * 8]);
    }
  };

  for (int hh = 0; hh < 2; ++hh) {
    const int T = hh ? (63 - pairId) : pairId;
    const int jmaxB = T * 4 + 3;
    const int jmaxW = T * 4 + wid * 2 + 1;
    const int rowbase = T * 128 + wid * 64;

    // Q fragments in registers: rows rowbase + r*16 + cl, depth kc*32 + g4*8
    bf16x8 qh[4][4], ql[4][4];
#pragma unroll
    for (int r = 0; r < 4; ++r) {
      const size_t qoff = ((size_t)rowbase + r * 16 + cl) * HD + g4 * 8;
#pragma unroll
      for (int kc = 0; kc < 4; ++kc) {
        qh[r][kc] = *(const bf16x8*)(q_hi + qoff + kc * 32);
        ql[r][kc] = *(const bf16x8*)(q_lo + qoff + kc * 32);
      }
    }

    float m_ri[4][4], l_ri[4][4];
    f32x4 o_acc[4][8];
#pragma unroll
    for (int r = 0; r < 4; ++r)
#pragma unroll
      for (int i = 0; i < 4; ++i) { m_ri[r][i] = -1e30f; l_ri[r][i] = 0.f; }
#pragma unroll
    for (int r = 0; r < 4; ++r)
#pragma unroll
      for (int c2 = 0; c2 < 8; ++c2) o_acc[r][c2] = f32x4{0.f, 0.f, 0.f, 0.f};

    if (chunk <= jmaxB) {
      int cur = 0;
      stage(chunk, 0);
      __syncthreads();
      for (int j = chunk; j <= jmaxB; j += NCH) {
        if (j + NCH <= jmaxB) stage(j + NCH, cur ^ 1);

        if (j <= jmaxW) {
          // ---- QK^T: 3-product split (hh + lh + hl)
          f32x4 s[4][2];
#pragma unroll
          for (int r = 0; r < 4; ++r)
#pragma unroll
            for (int c = 0; c < 2; ++c) s[r][c] = f32x4{0.f, 0.f, 0.f, 0.f};
#pragma unroll
          for (int kc = 0; kc < 4; ++kc) {
#pragma unroll
            for (int c = 0; c < 2; ++c) {
              const int kcol = c * 16 + cl;
              const int byte = (kcol * 16 + ((kc * 4 + g4) ^ (kcol & 7))) * 16;
              bf16x8 khf = *(const bf16x8*)((const char*)ls_kh[cur] + byte);
              bf16x8 klf = *(const bf16x8*)((const char*)ls_kl[cur] + byte);
#pragma unroll
              for (int r = 0; r < 4; ++r) {
                s[r][c] = __builtin_amdgcn_mfma_f32_16x16x32_bf16(qh[r][kc], khf, s[r][c], 0, 0, 0);
                s[r][c] = __builtin_amdgcn_mfma_f32_16x16x32_bf16(ql[r][kc], khf, s[r][c], 0, 0, 0);
                s[r][c] = __builtin_amdgcn_mfma_f32_16x16x32_bf16(qh[r][kc], klf, s[r][c], 0, 0, 0);
              }
            }
          }

          // causal mask (diagonal band only)
          if (j >= T * 4 + wid * 2) {
#pragma unroll
            for (int r = 0; r < 4; ++r)
#pragma unroll
              for (int c = 0; c < 2; ++c)
#pragma unroll
                for (int i = 0; i < 4; ++i) {
                  int col = j * KVB + c * 16 + cl;
                  int row = rowbase + r * 16 + g4 * 4 + i;
                  if (col > row) s[r][c][i] = -1e30f;
                }
          }

          // ---- defer-max online softmax (no shuffles in steady state)
          bool ok = true;
#pragma unroll
          for (int r = 0; r < 4; ++r)
#pragma unroll
            for (int i = 0; i < 4; ++i) {
              float mx = fmaxf(s[r][0][i], s[r][1][i]);
              ok = ok && (mx <= m_ri[r][i] + 8.0f);
            }
          if (!__all(ok)) {
#pragma unroll
            for (int r = 0; r < 4; ++r)
#pragma unroll
              for (int i = 0; i < 4; ++i) {
                float rm = fmaxf(s[r][0][i], s[r][1][i]);
                rm = fmaxf(rm, __shfl_xor(rm, 1));
                rm = fmaxf(rm, __shfl_xor(rm, 2));
                rm = fmaxf(rm, __shfl_xor(rm, 4));
                rm = fmaxf(rm, __shfl_xor(rm, 8));
                float mnew = fmaxf(m_ri[r][i], rm);
                float corr = __expf(m_ri[r][i] - mnew);
                l_ri[r][i] *= corr;
#pragma unroll
                for (int c2 = 0; c2 < 8; ++c2) o_acc[r][c2][i] *= corr;
                m_ri[r][i] = mnew;
              }
          }

          // p = exp(s - m) (clamped for masked), lane-partial l, P -> LDS bf16
#pragma unroll
          for (int r = 0; r < 4; ++r)
#pragma unroll
            for (int c = 0; c < 2; ++c)
#pragma unroll
              for (int i = 0; i < 4; ++i) {
                float sv = s[r][c][i];
                float p = (sv > -1e29f) ? __expf(sv - m_ri[r][i]) : 0.f;
                l_ri[r][i] += p;
                ((unsigned short*)pw)[(r * 16 + g4 * 4 + i) * 40 + c * 16 + cl] = f2bf(p);
              }

          // ---- PV: o += P @ V (A = P from wave-private LDS, B = vT rows)
          bf16x8 pa[4];
#pragma unroll
          for (int r = 0; r < 4; ++r)
            pa[r] = *(const bf16x8*)((const char*)pw + (r * 16 + cl) * 80 + g4 * 16);
#pragma unroll
          for (int c2 = 0; c2 < 8; ++c2) {
            const int d = c2 * 16 + cl;
            const int byte = (d * 4 + (g4 ^ ((d & 3) ^ ((d >> 2) & 3)))) * 16;
            bf16x8 vb = *(const bf16x8*)((const char*)ls_v[cur] + byte);
#pragma unroll
            for (int r = 0; r < 4; ++r)
              o_acc[r][c2] = __builtin_amdgcn_mfma_f32_16x16x32_bf16(pa[r], vb, o_acc[r][c2], 0, 0, 0);
          }
        }

        __syncthreads();
        cur ^= 1;
      }
    }

    // ---- write partials
    const int base = T * NCH + chunk;
#pragma unroll
    for (int r = 0; r < 4; ++r)
#pragma unroll
      for (int c2 = 0; c2 < 8; ++c2)
#pragma unroll
        for (int i = 0; i < 4; ++i)
          part_o[((size_t)base * 128 + wid * 64 + r * 16 + g4 * 4 + i) * HD + c2 * 16 + cl] = o_acc[r][c2][i];

#pragma unroll
    for (int r = 0; r < 4; ++r)
#pragma unroll
      for (int i = 0; i < 4; ++i) {
        float lv = l_ri[r][i];
        lv += __shfl_xor(lv, 1);
        lv += __shfl_xor(lv, 2);
        lv += __shfl_xor(lv, 4);
        lv += __shfl_xor(lv, 8);
        if (cl == 0) {
          int rl = wid * 64 + r * 16 + g4 * 4 + i;
          part_ml[base * 256 + rl]       = m_ri[r][i];
          part_ml[base * 256 + 128 + rl] = lv;
        }
      }
  }
}

// ---------------- merge the 8 column-chunk partials ----------------
__global__ __launch_bounds__(128)
void merge_kernel(const float* __restrict__ part_o, const float* __restrict__ part_ml,
                  float* __restrict__ out)
{
  const int row = blockIdx.x;
  const int T   = row >> 7;
  const int r   = row & 127;
  const int c   = threadIdx.x;

  float m[NCH], l[NCH];
  float mstar = -3e38f;
#pragma unroll
  for (int s = 0; s < NCH; ++s) {
    m[s] = part_ml[(T * NCH + s) * 256 + r];
    l[s] = part_ml[(T * NCH + s) * 256 + 128 + r];
    mstar = fmaxf(mstar, m[s]);
  }
  float num = 0.f, den = 0.f;
#pragma unroll
  for (int s = 0; s < NCH; ++s) {
    float wgt = __expf(m[s] - mstar);
    den += l[s] * wgt;
    num += wgt * part_o[((size_t)(T * NCH + s) * 128 + r) * HD + c];
  }
  out[(size_t)row * HD + c] = num / den;
}

extern "C" void kernel_launch(void* const* d_in, const int* in_sizes, int n_in,
                              void* d_out, int out_size, void* d_ws, size_t ws_size,
                              hipStream_t stream)
{
  const float* x  = (const float*)d_in[0];
  const float* wq = (const float*)d_in[1];
  const float* wk = (const float*)d_in[2];
  const float* wv = (const float*)d_in[3];
  float* out = (float*)d_out;

  unsigned short* p = (unsigned short*)d_ws;
  unsigned short* xh = p;  p += (size_t)S_LEN * D_DIM;       // 33.5 MB
  unsigned short* xl = p;  p += (size_t)S_LEN * D_DIM;       // 33.5 MB
  unsigned short* wTh = p; p += (size_t)3 * HD * D_DIM;
  unsigned short* wTl = p; p += (size_t)3 * HD * D_DIM;
  unsigned short* q_hi = p; p += (size_t)S_LEN * HD;
  unsigned short* q_lo = p; p += (size_t)S_LEN * HD;
  unsigned short* k_hi = p; p += (size_t)S_LEN * HD;
  unsigned short* k_lo = p; p += (size_t)S_LEN * HD;
  unsigned short* vT   = p; p += (size_t)S_LEN * HD;
  // partials alias the (dead after proj) xh/xl regions:
  float* part_o  = (float*)xh;   // 512 * 128 * 128 f32 = 33.55 MB (exact fit)
  float* part_ml = (float*)xl;   // 512 * 256 f32

  split_x_kernel<<<4096, 256, 0, stream>>>(x, xh, xl);
  split_w_kernel<<<dim3(32, 3), 256, 0, stream>>>(wq, wk, wv, wTh, wTl);
  proj_kernel<<<dim3(128, 3), 256, 0, stream>>>(xh, xl, wTh, wTl,
                                                q_hi, q_lo, k_hi, k_lo, vT);
  attn_kernel<<<dim3(256), 128, 0, stream>>>(q_hi, q_lo, k_hi, k_lo, vT,
                                             part_o, part_ml);
  merge_kernel<<<dim3(8192), 128, 0, stream>>>(part_o, part_ml, out);
}

// Round 5
// 151.099 us; speedup vs baseline: 2.1223x; 2.1223x over previous
//
#include <hip/hip_runtime.h>

#define S_LEN 8192
#define D_DIM 2048
#define HD    128
#define KVB   32       // kv tile rows
#define NCH   8        // kv chunks (flash-decoding split)

typedef __attribute__((ext_vector_type(8))) short bf16x8;
typedef __attribute__((ext_vector_type(4))) float f32x4;

__device__ __forceinline__ unsigned short f2bf(float f) {
  unsigned int u = __float_as_uint(f);
  u += 0x7fffu + ((u >> 16) & 1u);
  return (unsigned short)(u >> 16);
}
__device__ __forceinline__ float bf2f(unsigned short h) {
  return __uint_as_float(((unsigned int)h) << 16);
}

__device__ __forceinline__ void glds16(const void* g, const short* l) {
  __builtin_amdgcn_global_load_lds(
      (const __attribute__((address_space(1))) void*)g,
      (__attribute__((address_space(3))) void*)l, 16, 0, 0);
}

// ---------------- split x into hi/lo bf16 ----------------
__global__ __launch_bounds__(256)
void split_x_kernel(const float* __restrict__ x,
                    unsigned short* __restrict__ xh, unsigned short* __restrict__ xl)
{
  const size_t n4 = (size_t)S_LEN * D_DIM / 4;
  size_t idx = (size_t)blockIdx.x * 256 + threadIdx.x;
  const size_t stride = (size_t)gridDim.x * 256;
  for (; idx < n4; idx += stride) {
    float4 v = ((const float4*)x)[idx];
    ushort4 h, l;
#pragma unroll
    for (int j = 0; j < 4; ++j) {
      float f = ((const float*)&v)[j];
      unsigned short hb = f2bf(f);
      ((unsigned short*)&h)[j] = hb;
      ((unsigned short*)&l)[j] = f2bf(f - bf2f(hb));
    }
    ((ushort4*)xh)[idx] = h;
    ((ushort4*)xl)[idx] = l;
  }
}

// ---------------- transpose+split w: wT[mode][col][k] hi/lo bf16 ----------------
__global__ __launch_bounds__(256)
void split_w_kernel(const float* __restrict__ wq, const float* __restrict__ wk,
                    const float* __restrict__ wv,
                    unsigned short* __restrict__ wTh, unsigned short* __restrict__ wTl)
{
  const int mode = blockIdx.y;
  const float* __restrict__ w = (mode == 0) ? wq : (mode == 1) ? wk : wv;
  unsigned short* __restrict__ oh = wTh + (size_t)mode * HD * D_DIM;
  unsigned short* __restrict__ ol = wTl + (size_t)mode * HD * D_DIM;
  const int k0 = blockIdx.x * 64;

  __shared__ float ws[64][132];
  const int t = threadIdx.x;
#pragma unroll
  for (int i = 0; i < 8; ++i) {
    int idx = t + i * 256;
    int row = idx >> 5;
    int c4  = idx & 31;
    *(float4*)&ws[row][c4 * 4] = *(const float4*)(w + (size_t)(k0 + row) * HD + c4 * 4);
  }
  __syncthreads();
#pragma unroll
  for (int i = 0; i < 4; ++i) {
    int task = t + i * 256;
    int col = task >> 3;
    int kc  = task & 7;
    ushort4 h[2], l[2];
#pragma unroll
    for (int e = 0; e < 8; ++e) {
      float f = ws[kc * 8 + e][col];
      unsigned short hb = f2bf(f);
      ((unsigned short*)&h[e >> 2])[e & 3] = hb;
      ((unsigned short*)&l[e >> 2])[e & 3] = f2bf(f - bf2f(hb));
    }
    size_t off = (size_t)col * D_DIM + k0 + kc * 8;
    *(ushort4*)(oh + off)     = h[0];
    *(ushort4*)(oh + off + 4) = h[1];
    *(ushort4*)(ol + off)     = l[0];
    *(ushort4*)(ol + off + 4) = l[1];
  }
}

// ---------------- projection GEMM: split-bf16 MFMA ----------------
__global__ __launch_bounds__(256)
void proj_kernel(const unsigned short* __restrict__ xh, const unsigned short* __restrict__ xl,
                 const unsigned short* __restrict__ wTh, const unsigned short* __restrict__ wTl,
                 unsigned short* __restrict__ q_hi, unsigned short* __restrict__ q_lo,
                 unsigned short* __restrict__ k_hi, unsigned short* __restrict__ k_lo,
                 unsigned short* __restrict__ vT)
{
  __shared__ short sm[2][12288];

  const int mode = blockIdx.y;
  const int mt   = blockIdx.x;
  const bool split = (mode < 2);

  const unsigned short* gxh = xh + (size_t)mt * 64 * D_DIM;
  const unsigned short* gxl = xl + (size_t)mt * 64 * D_DIM;
  const unsigned short* gwh = wTh + (size_t)mode * HD * D_DIM;
  const unsigned short* gwl = wTl + (size_t)mode * HD * D_DIM;

  const int t   = threadIdx.x;
  const int wid = t >> 6;
  const int ln  = t & 63;
  const int cl  = ln & 15;
  const int g4  = ln >> 4;

  auto stage = [&](int kt, int buf) {
    short* b = sm[buf];
    {
      int slot = wid * 64 + ln;
      int row = slot >> 2, sc = slot & 3;
      int kof = (sc ^ (row & 3)) * 8;
      glds16(gxh + (size_t)row * D_DIM + kt + kof, b + wid * 512);
      if (split)
        glds16(gxl + (size_t)row * D_DIM + kt + kof, b + 2048 + wid * 512);
    }
#pragma unroll
    for (int g = 0; g < 2; ++g) {
      int slot = g * 256 + wid * 64 + ln;
      int col = slot >> 2, sc = slot & 3;
      int kof = (sc ^ (col & 3)) * 8;
      glds16(gwh + (size_t)col * D_DIM + kt + kof, b + 4096 + (g * 256 + wid * 64) * 8);
      if (split)
        glds16(gwl + (size_t)col * D_DIM + kt + kof, b + 8192 + (g * 256 + wid * 64) * 8);
    }
  };

  f32x4 acc[2][4];
#pragma unroll
  for (int m = 0; m < 2; ++m)
#pragma unroll
    for (int n = 0; n < 4; ++n) acc[m][n] = f32x4{0.f, 0.f, 0.f, 0.f};

  stage(0, 0);
  __syncthreads();

  for (int kt = 0, step = 0; kt < D_DIM; kt += 32, ++step) {
    const int cur = step & 1;
    if (kt + 32 < D_DIM) stage(kt + 32, cur ^ 1);

    const short* b = sm[cur];
    bf16x8 a_h[2], a_l[2], b_h[4], b_l[4];
#pragma unroll
    for (int m = 0; m < 2; ++m) {
      int row = (wid >> 1) * 32 + m * 16 + cl;
      int byte = row * 64 + ((g4 ^ (row & 3)) << 4);
      a_h[m] = *(const bf16x8*)((const char*)b + byte);
      if (split) a_l[m] = *(const bf16x8*)((const char*)b + 4096 + byte);
    }
#pragma unroll
    for (int n = 0; n < 4; ++n) {
      int col = (wid & 1) * 64 + n * 16 + cl;
      int byte = col * 64 + ((g4 ^ (col & 3)) << 4);
      b_h[n] = *(const bf16x8*)((const char*)b + 8192 + byte);
      if (split) b_l[n] = *(const bf16x8*)((const char*)b + 16384 + byte);
    }

#pragma unroll
    for (int m = 0; m < 2; ++m)
#pragma unroll
      for (int n = 0; n < 4; ++n)
        acc[m][n] = __builtin_amdgcn_mfma_f32_16x16x32_bf16(a_h[m], b_h[n], acc[m][n], 0, 0, 0);
    if (split) {
#pragma unroll
      for (int m = 0; m < 2; ++m)
#pragma unroll
        for (int n = 0; n < 4; ++n) {
          acc[m][n] = __builtin_amdgcn_mfma_f32_16x16x32_bf16(a_l[m], b_h[n], acc[m][n], 0, 0, 0);
          acc[m][n] = __builtin_amdgcn_mfma_f32_16x16x32_bf16(a_h[m], b_l[n], acc[m][n], 0, 0, 0);
        }
    }
    __syncthreads();
  }

  const int rbase = mt * 64 + (wid >> 1) * 32 + g4 * 4;
  const int cbase = (wid & 1) * 64 + cl;

  if (mode < 2) {
    const float scale = (mode == 0) ? 0.08838834764831843f : 1.0f;
    unsigned short* __restrict__ oh = (mode == 0) ? q_hi : k_hi;
    unsigned short* __restrict__ ol = (mode == 0) ? q_lo : k_lo;
#pragma unroll
    for (int m = 0; m < 2; ++m)
#pragma unroll
      for (int n = 0; n < 4; ++n)
#pragma unroll
        for (int r = 0; r < 4; ++r) {
          float val = acc[m][n][r] * scale;
          unsigned short hb = f2bf(val);
          size_t off = (size_t)(rbase + m * 16 + r) * HD + cbase + n * 16;
          oh[off] = hb;
          ol[off] = f2bf(val - bf2f(hb));
        }
  } else {
#pragma unroll
    for (int m = 0; m < 2; ++m)
#pragma unroll
      for (int n = 0; n < 4; ++n) {
        ushort4 o;
#pragma unroll
        for (int r = 0; r < 4; ++r) ((unsigned short*)&o)[r] = f2bf(acc[m][n][r]);
        int col = cbase + n * 16;
        *(ushort4*)(vT + (size_t)col * S_LEN + rbase + m * 16) = o;
      }
  }
}

// ---------------- MFMA flash attention v3 ----------------
// r3 skeleton (4 waves x 16 q-rows, 64-row tiles) + KVB=32 (53 KB LDS -> 3 blk/CU)
// + NCH=8 (grid 512) + 3-product QK^T + defer-max/deferred-l softmax.
__global__ __launch_bounds__(256, 3)
void attn_kernel(const unsigned short* __restrict__ q_hi, const unsigned short* __restrict__ q_lo,
                 const unsigned short* __restrict__ k_hi, const unsigned short* __restrict__ k_lo,
                 const unsigned short* __restrict__ vT,
                 float* __restrict__ part_o, float* __restrict__ part_ml)
{
  __shared__ short ls_kh[2][4096];   // K hi: 32 x 128 bf16, chunk-swizzled
  __shared__ short ls_kl[2][4096];   // K lo
  __shared__ short ls_v [2][4096];   // v^T: 128 x 32 bf16, swizzled
  __shared__ short ls_p [4][640];    // per-wave P [16][40]

  const int t   = threadIdx.x;
  const int wid = t >> 6;
  const int ln  = t & 63;
  const int cl  = ln & 15;
  const int g4  = ln >> 4;
  const int pairId = blockIdx.x >> 3;   // 0..63
  const int chunk  = blockIdx.x & 7;

  short* pw = ls_p[wid];

  auto stage = [&](int j, int buf) {
    const unsigned short* gkh = k_hi + (size_t)j * KVB * HD;
    const unsigned short* gkl = k_lo + (size_t)j * KVB * HD;
    const unsigned short* gv  = vT + (size_t)j * KVB;
#pragma unroll
    for (int i = 0; i < 2; ++i) {
      int slot = wid * 128 + i * 64 + ln;
      int row = slot >> 4, sc = slot & 15;
      int c16 = sc ^ (row & 7);
      glds16(gkh + row * HD + c16 * 8, &ls_kh[buf][(wid * 128 + i * 64) * 8]);
      glds16(gkl + row * HD + c16 * 8, &ls_kl[buf][(wid * 128 + i * 64) * 8]);
    }
#pragma unroll
    for (int i = 0; i < 2; ++i) {
      int slot = wid * 128 + i * 64 + ln;
      int d = slot >> 2, sub = slot & 3;
      int s2 = sub ^ ((d >> 1) & 3);
      glds16(gv + (size_t)d * S_LEN + s2 * 8, &ls_v[buf][(wid * 128 + i * 64) * 8]);
    }
  };

  for (int hh = 0; hh < 2; ++hh) {
    const int T = hh ? (127 - pairId) : pairId;
    const int jmaxB = T * 2 + 1;
    const int jmaxW = T * 2 + (wid >> 1);
    const int rowbase = T * 64 + wid * 16;

    // Q fragments in registers (A-layout: row=cl, k = kc*32 + g4*8 + e)
    bf16x8 qh[4], ql[4];
    {
      const size_t qoff = ((size_t)rowbase + cl) * HD + g4 * 8;
#pragma unroll
      for (int kc = 0; kc < 4; ++kc) {
        qh[kc] = *(const bf16x8*)(q_hi + qoff + kc * 32);
        ql[kc] = *(const bf16x8*)(q_lo + qoff + kc * 32);
      }
    }

    float m_i[4], l_i[4];
    f32x4 o_acc[8];
#pragma unroll
    for (int i = 0; i < 4; ++i) { m_i[i] = -1e30f; l_i[i] = 0.f; }
#pragma unroll
    for (int c = 0; c < 8; ++c) o_acc[c] = f32x4{0.f, 0.f, 0.f, 0.f};

    if (chunk <= jmaxB) {
      int cur = 0;
      stage(chunk, 0);
      __syncthreads();
      for (int j = chunk; j <= jmaxB; j += NCH) {
        if (j + NCH <= jmaxB) stage(j + NCH, cur ^ 1);

        if (j <= jmaxW) {
          // ---- QK^T: 3-product split (hh + lh + hl)
          f32x4 s[2];
          s[0] = f32x4{0.f, 0.f, 0.f, 0.f};
          s[1] = f32x4{0.f, 0.f, 0.f, 0.f};
#pragma unroll
          for (int kc = 0; kc < 4; ++kc) {
#pragma unroll
            for (int c = 0; c < 2; ++c) {
              const int kcol = c * 16 + cl;
              const int byte = kcol * 256 + ((((kc << 2) + g4) ^ (kcol & 7)) << 4);
              bf16x8 khf = *(const bf16x8*)((const char*)ls_kh[cur] + byte);
              bf16x8 klf = *(const bf16x8*)((const char*)ls_kl[cur] + byte);
              s[c] = __builtin_amdgcn_mfma_f32_16x16x32_bf16(qh[kc], khf, s[c], 0, 0, 0);
              s[c] = __builtin_amdgcn_mfma_f32_16x16x32_bf16(ql[kc], khf, s[c], 0, 0, 0);
              s[c] = __builtin_amdgcn_mfma_f32_16x16x32_bf16(qh[kc], klf, s[c], 0, 0, 0);
            }
          }

          // causal mask (only when the kv tile crosses the diagonal)
          if (j * KVB + KVB - 1 > rowbase) {
#pragma unroll
            for (int c = 0; c < 2; ++c)
#pragma unroll
              for (int i = 0; i < 4; ++i) {
                int col = j * KVB + c * 16 + cl;
                int row = rowbase + g4 * 4 + i;
                if (col > row) s[c][i] = -1e30f;
              }
          }

          // ---- defer-max online softmax (shuffle-free steady state)
          bool ok = true;
#pragma unroll
          for (int i = 0; i < 4; ++i) {
            float mx = fmaxf(s[0][i], s[1][i]);
            ok = ok && (mx <= m_i[i] + 8.0f);
          }
          if (!__all(ok)) {
#pragma unroll
            for (int i = 0; i < 4; ++i) {
              float rm = fmaxf(s[0][i], s[1][i]);
              rm = fmaxf(rm, __shfl_xor(rm, 1));
              rm = fmaxf(rm, __shfl_xor(rm, 2));
              rm = fmaxf(rm, __shfl_xor(rm, 4));
              rm = fmaxf(rm, __shfl_xor(rm, 8));
              float mnew = fmaxf(m_i[i], rm);
              float corr = __expf(m_i[i] - mnew);
              l_i[i] *= corr;
#pragma unroll
              for (int c2 = 0; c2 < 8; ++c2) o_acc[c2][i] *= corr;
              m_i[i] = mnew;
            }
          }

          // p = exp(s - m) (0 for masked), lane-partial l, P -> wave LDS (bf16)
#pragma unroll
          for (int c = 0; c < 2; ++c)
#pragma unroll
            for (int i = 0; i < 4; ++i) {
              float sv = s[c][i];
              float p = (sv > -1e29f) ? __expf(sv - m_i[i]) : 0.f;
              l_i[i] += p;
              pw[(g4 * 4 + i) * 40 + c * 16 + cl] = (short)f2bf(p);
            }

          // ---- PV: o += P @ V (A-frag from wave LDS, B-frag = vT rows)
          bf16x8 pa = *(const bf16x8*)((const char*)pw + cl * 80 + g4 * 16);
#pragma unroll
          for (int c2 = 0; c2 < 8; ++c2) {
            const int d = c2 * 16 + cl;
            const int byte = d * 64 + (((g4 ^ ((d >> 1) & 3))) << 4);
            bf16x8 vb = *(const bf16x8*)((const char*)ls_v[cur] + byte);
            o_acc[c2] = __builtin_amdgcn_mfma_f32_16x16x32_bf16(pa, vb, o_acc[c2], 0, 0, 0);
          }
        }

        __syncthreads();
        cur ^= 1;
      }
    }

    // ---- write partials (unconditional; zeros when no work)
    const int base = T * NCH + chunk;
#pragma unroll
    for (int c2 = 0; c2 < 8; ++c2)
#pragma unroll
      for (int i = 0; i < 4; ++i)
        part_o[((size_t)base * 64 + wid * 16 + g4 * 4 + i) * HD + c2 * 16 + cl] = o_acc[c2][i];

#pragma unroll
    for (int i = 0; i < 4; ++i) {
      float lv = l_i[i];
      lv += __shfl_xor(lv, 1);
      lv += __shfl_xor(lv, 2);
      lv += __shfl_xor(lv, 4);
      lv += __shfl_xor(lv, 8);
      if (cl == 0) {
        int rl = wid * 16 + g4 * 4 + i;
        part_ml[base * 128 + rl]      = m_i[i];
        part_ml[base * 128 + 64 + rl] = lv;
      }
    }
  }
}

// ---------------- merge the 8 column-chunk partials ----------------
__global__ __launch_bounds__(128)
void merge_kernel(const float* __restrict__ part_o, const float* __restrict__ part_ml,
                  float* __restrict__ out)
{
  const int row = blockIdx.x;
  const int T   = row >> 6;
  const int r   = row & 63;
  const int c   = threadIdx.x;

  float m[NCH], l[NCH];
  float mstar = -3e38f;
#pragma unroll
  for (int s = 0; s < NCH; ++s) {
    m[s] = part_ml[(T * NCH + s) * 128 + r];
    l[s] = part_ml[(T * NCH + s) * 128 + 64 + r];
    mstar = fmaxf(mstar, m[s]);
  }
  float num = 0.f, den = 0.f;
#pragma unroll
  for (int s = 0; s < NCH; ++s) {
    float wgt = __expf(m[s] - mstar);
    den += l[s] * wgt;
    num += wgt * part_o[((size_t)(T * NCH + s) * 64 + r) * HD + c];
  }
  out[(size_t)row * HD + c] = num / den;
}

extern "C" void kernel_launch(void* const* d_in, const int* in_sizes, int n_in,
                              void* d_out, int out_size, void* d_ws, size_t ws_size,
                              hipStream_t stream)
{
  const float* x  = (const float*)d_in[0];
  const float* wq = (const float*)d_in[1];
  const float* wk = (const float*)d_in[2];
  const float* wv = (const float*)d_in[3];
  float* out = (float*)d_out;

  unsigned short* p = (unsigned short*)d_ws;
  unsigned short* xh = p;  p += (size_t)S_LEN * D_DIM;       // 33.5 MB
  unsigned short* xl = p;  p += (size_t)S_LEN * D_DIM;       // 33.5 MB
  unsigned short* wTh = p; p += (size_t)3 * HD * D_DIM;
  unsigned short* wTl = p; p += (size_t)3 * HD * D_DIM;
  unsigned short* q_hi = p; p += (size_t)S_LEN * HD;
  unsigned short* q_lo = p; p += (size_t)S_LEN * HD;
  unsigned short* k_hi = p; p += (size_t)S_LEN * HD;
  unsigned short* k_lo = p; p += (size_t)S_LEN * HD;
  unsigned short* vT   = p; p += (size_t)S_LEN * HD;
  // partials alias the (dead after proj) xh/xl regions:
  float* part_o  = (float*)xh;   // 1024 bases * 64 rows * 128 f32 = 33.55 MB (exact fit)
  float* part_ml = (float*)xl;   // 1024 * 128 f32

  split_x_kernel<<<4096, 256, 0, stream>>>(x, xh, xl);
  split_w_kernel<<<dim3(32, 3), 256, 0, stream>>>(wq, wk, wv, wTh, wTl);
  proj_kernel<<<dim3(128, 3), 256, 0, stream>>>(xh, xl, wTh, wTl,
                                                q_hi, q_lo, k_hi, k_lo, vT);
  attn_kernel<<<dim3(512), 256, 0, stream>>>(q_hi, q_lo, k_hi, k_lo, vT,
                                             part_o, part_ml);
  merge_kernel<<<dim3(8192), 128, 0, stream>>>(part_o, part_ml, out);
}